// Round 3
// baseline (678.529 us; speedup 1.0000x reference)
//
#include <hip/hip_runtime.h>
#include <math.h>

#define N_TOK 8192
#define HID   8192
#define NG    16
#define NE    16
#define KC    256              // K floats per chunk (16 KB weight tile)
#define NCHUNK (HID / KC)      // 32
#define TPB   16               // tokens per block tile (bucketing granularity)
#define TPW   4                // tokens per wave; 4 waves x 4 tokens = TPB

// ---- ws layout (bytes) ----
#define OFF_CNT   0u
#define OFF_GSUM  64u
#define OFF_ESUM  128u
#define OFF_NTIL  192u
#define ZERO_BYTES 256u
#define OFF_BUCK  256u                               // int[16][8192]
#define OFF_SCHED (OFF_BUCK + NG*N_TOK*4)            // int[2048]
#define OFF_MGT   (OFF_SCHED + 2048*4)               // float[16][16][8192] 16 MiB

// global -> LDS DMA, 16B per lane; LDS dest = uniform base + lane*16
__device__ __forceinline__ void glds16(const float* gp, float* lp) {
    __builtin_amdgcn_global_load_lds(
        (const __attribute__((address_space(1))) void*)gp,
        (__attribute__((address_space(3))) void*)lp, 16, 0, 0);
}

// cross-lane fp32 reduce-scatter round on 64 accs: halves live acc count.
// After rounds (32..1), lane L holds original acc index L.
#define RS_ROUND(o, half)                                                 \
  {                                                                       \
    const bool hi_ = (lane & (o)) != 0;                                   \
    _Pragma("unroll")                                                     \
    for (int i_ = 0; i_ < (half); ++i_) {                                 \
      float s_ = hi_ ? acc[i_] : acc[i_ + (half)];                        \
      float r_ = __shfl_xor(s_, (o));                                     \
      acc[i_] = (hi_ ? acc[i_ + (half)] : acc[i_]) + r_;                  \
    }                                                                     \
  }

// One K-chunk: counted-vmcnt pipeline (T3/T4-lite).
//  entry: outstanding = DMA(c) x4 (oldest) + hid(c) x4  -> vmcnt(4) drains DMA(c) only
//  s_barrier: all waves' DMA(c) landed -> buf[c&1] valid (no vmcnt(0) drain!)
//  then issue DMA(c+1) (safe: everyone finished reading buf[(c+1)&1] in iter c-1),
//  then hid(c+1); sched_barrier pins DMA-before-hid issue order so the
//  "4 newest" at next entry are exactly hid(c+1).
#define GBODY(c, ACOMP, ALOAD, WB)                                        \
  {                                                                       \
    asm volatile("s_waitcnt vmcnt(4)" ::: "memory");                      \
    __builtin_amdgcn_s_barrier();                                         \
    __builtin_amdgcn_sched_barrier(0);                                    \
    if ((c) + 1 < NCHUNK) {                                               \
      const int kn_ = ((c) + 1) * KC;                                     \
      _Pragma("unroll")                                                   \
      for (int j_ = 0; j_ < 4; ++j_)                                      \
        glds16(WB + (size_t)(wv * 4 + j_) * HID + kn_ + 4 * lane,         \
               &Wl[((c) + 1) & 1][(wv * 4 + j_) * KC]);                   \
      __builtin_amdgcn_sched_barrier(0);                                  \
      _Pragma("unroll")                                                   \
      for (int t_ = 0; t_ < TPW; ++t_)                                    \
        ALOAD[t_] = *(const float4*)&at[t_][kn_];                         \
    }                                                                     \
    const float* Wc_ = &Wl[(c) & 1][0];                                   \
    _Pragma("unroll")                                                     \
    for (int g_ = 0; g_ < NG; ++g_) {                                     \
      float4 w_ = *(const float4*)&Wc_[g_ * KC + 4 * lane];               \
      _Pragma("unroll")                                                   \
      for (int t_ = 0; t_ < TPW; ++t_) {                                  \
        acc[t_*16+g_] = fmaf(ACOMP[t_].x, w_.x, acc[t_*16+g_]);           \
        acc[t_*16+g_] = fmaf(ACOMP[t_].y, w_.y, acc[t_*16+g_]);           \
        acc[t_*16+g_] = fmaf(ACOMP[t_].z, w_.z, acc[t_*16+g_]);           \
        acc[t_*16+g_] = fmaf(ACOMP[t_].w, w_.w, acc[t_*16+g_]);           \
      }                                                                   \
    }                                                                     \
  }

// ---------------- Tier-1: group logits + fused softmax/argmax/bucket ----------------
__global__ __launch_bounds__(256, 3) void k_group(
    const float* __restrict__ hid, const float* __restrict__ gw,
    int* __restrict__ cnt, int* __restrict__ buckets, float* __restrict__ gsum)
{
    __shared__ float Wl[2][NG * KC];                 // 2 x 16 KB
    const int tid  = threadIdx.x;
    const int lane = tid & 63;
    const int wv   = tid >> 6;                       // 0..3
    const int t0   = blockIdx.x * TPB + wv * TPW;    // wave owns 4 tokens

    #pragma unroll
    for (int j = 0; j < 4; ++j)                      // DMA chunk 0: 4 rows per wave
        glds16(gw + (size_t)(wv * 4 + j) * HID + 4 * lane, &Wl[0][(wv * 4 + j) * KC]);
    __builtin_amdgcn_sched_barrier(0);               // keep DMA issued before hid loads

    const float* at[TPW];
    #pragma unroll
    for (int t = 0; t < TPW; ++t) at[t] = hid + (size_t)(t0 + t) * HID + 4 * lane;

    float4 aregA[TPW], aregB[TPW];
    #pragma unroll
    for (int t = 0; t < TPW; ++t) aregA[t] = *(const float4*)&at[t][0];

    float acc[64];                                   // [t][g]
    #pragma unroll
    for (int i = 0; i < 64; ++i) acc[i] = 0.f;

    #pragma unroll 1
    for (int c = 0; c < NCHUNK; c += 2) {
        GBODY(c,     aregA, aregB, gw)
        GBODY(c + 1, aregB, aregA, gw)
    }

    RS_ROUND(32, 32) RS_ROUND(16, 16) RS_ROUND(8, 8)
    RS_ROUND(4, 4)   RS_ROUND(2, 2)   RS_ROUND(1, 1)
    // lane holds logit for (t = lane>>4, g = lane&15)
    float v = acc[0];
    float mx = v;
    #pragma unroll
    for (int o = 8; o; o >>= 1) mx = fmaxf(mx, __shfl_xor(mx, o));
    float p = expf(v - mx);
    float s = p;
    #pragma unroll
    for (int o = 8; o; o >>= 1) s += __shfl_xor(s, o);
    p /= s;
    float x = p;                                     // sum probs over wave's 4 tokens
    x += __shfl_xor(x, 16);
    x += __shfl_xor(x, 32);
    if (lane < 16) unsafeAtomicAdd(&gsum[lane], x);
    int gi = lane & 15; float bv = v;                // first-index-wins argmax on fp32
    #pragma unroll
    for (int o = 8; o; o >>= 1) {
        float ov = __shfl_xor(bv, o);
        int   og = __shfl_xor(gi, o);
        if (ov > bv || (ov == bv && og < gi)) { bv = ov; gi = og; }
    }
    if ((lane & 15) == 0) {                          // one leader per token
        int t = t0 + (lane >> 4);
        int pos = atomicAdd(&cnt[gi], 1);
        buckets[gi * N_TOK + pos] = t;
    }
}

// ---------------- mg [g][k][e] -> mgT [g][e][k], full K coverage ----------------
__global__ __launch_bounds__(256) void k_tr(
    const float* __restrict__ mg, float* __restrict__ mgT)
{
    const int g  = blockIdx.x >> 7;                  // 16 g x 128 k-blocks = 2048 blocks
    const int kb = (blockIdx.x & 127) * 64;          // 64 k per block -> covers k 0..8191
    const int e  = threadIdx.x & 15;
    const int kq = threadIdx.x >> 4;                 // 0..15
    const int k0 = kb + 4 * kq;
    const float* src = mg + (size_t)g * HID * NE;
    float4 v;
    v.x = src[(size_t)(k0 + 0) * NE + e];
    v.y = src[(size_t)(k0 + 1) * NE + e];
    v.z = src[(size_t)(k0 + 2) * NE + e];
    v.w = src[(size_t)(k0 + 3) * NE + e];
    *(float4*)&mgT[(size_t)(g * NE + e) * HID + k0] = v;   // coalesced writes
}

// ---------------- build compact (group,tile) worklist ----------------
__global__ void k_sched(const int* __restrict__ cnt, int* __restrict__ sched,
                        int* __restrict__ ntile)
{
    __shared__ int pref[NG + 1];
    if (threadIdx.x == 0) {
        int s = 0;
        for (int g = 0; g < NG; ++g) { pref[g] = s; s += (cnt[g] + TPB - 1) / TPB; }
        pref[NG] = s; *ntile = s;
    }
    __syncthreads();
    int total = pref[NG];
    for (int i = threadIdx.x; i < total; i += blockDim.x) {
        int g = 0;
        while (g < NG - 1 && i >= pref[g + 1]) ++g;
        sched[i] = (g << 16) | (i - pref[g]);
    }
}

// ---------------- Tier-2: mini logits + fused softmax/top-4/output ----------------
__global__ __launch_bounds__(256, 3) void k_mini(
    const float* __restrict__ hid, const float* __restrict__ mgT,
    const int* __restrict__ cnt, const int* __restrict__ buckets,
    const int* __restrict__ sched, const int* __restrict__ ntile,
    float* __restrict__ out, float* __restrict__ esum)
{
    if ((int)blockIdx.x >= *ntile) return;
    const int enc  = sched[blockIdx.x];
    const int g    = enc >> 16;
    const int tile = enc & 0xffff;
    const int n    = cnt[g] - tile * TPB;            // 1..16 valid tokens

    __shared__ float Wl[2][NE * KC];                 // 2 x 16 KB
    __shared__ int   rows[TPB];
    __shared__ float sm[256];
    const int tid  = threadIdx.x;
    const int lane = tid & 63;
    const int wv   = tid >> 6;                       // 0..3
    const float* __restrict__ wg = mgT + (size_t)g * NE * HID;

    #pragma unroll
    for (int j = 0; j < 4; ++j)                      // DMA chunk 0 (independent of rows)
        glds16(wg + (size_t)(wv * 4 + j) * HID + 4 * lane, &Wl[0][(wv * 4 + j) * KC]);
    if (tid < TPB)
        rows[tid] = buckets[g * N_TOK + tile * TPB + min(tid, n - 1)];  // clamp dup tail
    __syncthreads();                                 // drains DMA(0) too (once, ok)

    const float* at[TPW];
    #pragma unroll
    for (int t = 0; t < TPW; ++t)
        at[t] = hid + (size_t)rows[wv * TPW + t] * HID + 4 * lane;

    float4 aregA[TPW], aregB[TPW];
    #pragma unroll
    for (int t = 0; t < TPW; ++t) aregA[t] = *(const float4*)&at[t][0];

    float acc[64];
    #pragma unroll
    for (int i = 0; i < 64; ++i) acc[i] = 0.f;

    #pragma unroll 1
    for (int c = 0; c < NCHUNK; c += 2) {
        GBODY(c,     aregA, aregB, wg)
        GBODY(c + 1, aregB, aregA, wg)
    }

    RS_ROUND(32, 32) RS_ROUND(16, 16) RS_ROUND(8, 8)
    RS_ROUND(4, 4)   RS_ROUND(2, 2)   RS_ROUND(1, 1)
    // lane holds logit for (tl = wv*4 + (lane>>4), e = lane&15)
    const int tl = wv * TPW + (lane >> 4);
    float v = acc[0];
    float mx = v;
    #pragma unroll
    for (int o = 8; o; o >>= 1) mx = fmaxf(mx, __shfl_xor(mx, o));
    float p = expf(v - mx);
    float s = p;
    #pragma unroll
    for (int o = 8; o; o >>= 1) s += __shfl_xor(s, o);
    p /= s;
    float x = (tl < n) ? p : 0.f;                    // exclude dup-clamped tail tokens
    x += __shfl_xor(x, 16);
    x += __shfl_xor(x, 32);
    if (lane < 16) unsafeAtomicAdd(&esum[lane], x);

    sm[tid] = p;                                     // sm[tl*16 + e] == sm[tid]
    __syncthreads();
    if ((tid & 15) == 0) {                           // leader per token
        int tt = tid >> 4;                           // == tl
        if (tt < n) {
            float pe[NE];
            #pragma unroll
            for (int e = 0; e < NE; ++e) pe[e] = sm[tt * 16 + e];
            unsigned used = 0;
            float tv[4]; int ti[4];
            #pragma unroll
            for (int j = 0; j < 4; ++j) {
                float best = -1.f; int bi = 0;
                #pragma unroll
                for (int e = 0; e < NE; ++e)
                    if (!((used >> e) & 1u) && pe[e] > best) { best = pe[e]; bi = e; }
                used |= 1u << bi; tv[j] = best; ti[j] = bi;
            }
            float inv4 = 1.f / (tv[0] + tv[1] + tv[2] + tv[3]);   // group prob cancels
            int t = rows[tt];
            #pragma unroll
            for (int j = 0; j < 4; ++j) {
                out[t * 4 + j]             = tv[j] * inv4;
                out[N_TOK * 4 + t * 4 + j] = (float)(g * NE + ti[j]);
            }
        }
    }
}

// ---------------- aux loss scalar ----------------
__global__ void k_aux(const float* __restrict__ gsum, const float* __restrict__ esum,
                      float* __restrict__ out)
{
    if (threadIdx.x == 0) {
        float a = 0.f;
        for (int g = 0; g < NG; ++g) { float m = gsum[g] * (1.f / N_TOK); a += m * m; }
        for (int e = 0; e < NE; ++e) { float m = esum[e] * (1.f / N_TOK); a += m * m; }
        out[N_TOK * 8] = a;   // element 65536
    }
}

extern "C" void kernel_launch(void* const* d_in, const int* in_sizes, int n_in,
                              void* d_out, int out_size, void* d_ws, size_t ws_size,
                              hipStream_t stream) {
    const float* hid = (const float*)d_in[0];   // [8192,8192]
    const float* gw  = (const float*)d_in[1];   // [16,8192]
    const float* mg  = (const float*)d_in[2];   // [16,8192,16]
    float* out = (float*)d_out;
    char*  ws  = (char*)d_ws;
    int*    cnt     = (int*)   (ws + OFF_CNT);
    float*  gsum    = (float*) (ws + OFF_GSUM);
    float*  esum    = (float*) (ws + OFF_ESUM);
    int*    ntile   = (int*)   (ws + OFF_NTIL);
    int*    buckets = (int*)   (ws + OFF_BUCK);
    int*    sched   = (int*)   (ws + OFF_SCHED);
    float*  mgT     = (float*) (ws + OFF_MGT);

    hipMemsetAsync(d_ws, 0, ZERO_BYTES, stream);

    k_tr<<<2048, 256, 0, stream>>>(mg, mgT);
    k_group<<<N_TOK / TPB, 256, 0, stream>>>(hid, gw, cnt, buckets, gsum);
    k_sched<<<1, 256, 0, stream>>>(cnt, sched, ntile);
    k_mini<<<N_TOK / TPB + NG, 256, 0, stream>>>(hid, mgT, cnt, buckets, sched, ntile, out, esum);
    k_aux<<<1, 64, 0, stream>>>(gsum, esum, out);
}

// Round 4
// 551.827 us; speedup vs baseline: 1.2296x; 1.2296x over previous
//
#include <hip/hip_runtime.h>
#include <math.h>

#define N_TOK 8192
#define HID   8192
#define NG    16
#define NE    16
#define KC    256              // K floats per chunk (16 KB weight tile)
#define NCHUNK (HID / KC)      // 32
#define TPB   8                // tokens per block tile (bucketing granularity)
#define TPW   2                // tokens per wave; 4 waves x 2 tokens = TPB

// ---- ws layout (bytes) ----
#define OFF_CNT   0u
#define OFF_GSUM  64u
#define OFF_ESUM  128u
#define OFF_NTIL  192u
#define ZERO_BYTES 256u
#define OFF_BUCK  256u                               // int[16][8192]
#define OFF_SCHED (OFF_BUCK + NG*N_TOK*4)            // int[2048]
#define OFF_MGT   (OFF_SCHED + 2048*4)               // float[16][16][8192] 16 MiB

// global -> LDS DMA, 16B per lane; LDS dest = uniform base + lane*16
__device__ __forceinline__ void glds16(const float* gp, float* lp) {
    __builtin_amdgcn_global_load_lds(
        (const __attribute__((address_space(1))) void*)gp,
        (__attribute__((address_space(3))) void*)lp, 16, 0, 0);
}

// cross-lane fp32 reduce-scatter round: halves live acc count.
#define RS_ROUND(o, half)                                                 \
  {                                                                       \
    const bool hi_ = (lane & (o)) != 0;                                   \
    _Pragma("unroll")                                                     \
    for (int i_ = 0; i_ < (half); ++i_) {                                 \
      float s_ = hi_ ? acc[i_] : acc[i_ + (half)];                        \
      float r_ = __shfl_xor(s_, (o));                                     \
      acc[i_] = (hi_ ? acc[i_ + (half)] : acc[i_]) + r_;                  \
    }                                                                     \
  }

// ---------------- Tier-1: group logits + fused softmax/argmax/bucket ----------------
// R1-verified structure (LDS dbuf + __syncthreads drain per chunk), but with
// 4-wave blocks and grid=1024 so ~4 independent blocks/CU hide each other's
// barrier drains (TLP latency hiding; 2 blocks/CU was the R1 limiter).
__global__ __launch_bounds__(256, 4) void k_group(
    const float* __restrict__ hid, const float* __restrict__ gw,
    int* __restrict__ cnt, int* __restrict__ buckets, float* __restrict__ gsum)
{
    __shared__ float Wl[2][NG * KC];                 // 2 x 16 KB
    const int tid  = threadIdx.x;
    const int lane = tid & 63;
    const int wv   = tid >> 6;                       // 0..3
    const int t0   = blockIdx.x * TPB + wv * TPW;    // wave owns 2 tokens
    const float* __restrict__ a0 = hid + (size_t)t0 * HID;

    #pragma unroll
    for (int j = 0; j < 4; ++j)                      // DMA W chunk0: 4 rows/wave (1KB each)
        glds16(gw + (size_t)(wv * 4 + j) * HID + 4 * lane, &Wl[0][(wv * 4 + j) * KC]);

    float4 areg[TPW];
    #pragma unroll
    for (int t = 0; t < TPW; ++t)
        areg[t] = *(const float4*)&a0[(size_t)t * HID + 4 * lane];

    float acc[32];                                   // [t][g]
    #pragma unroll
    for (int i = 0; i < 32; ++i) acc[i] = 0.f;

    for (int c = 0; c < NCHUNK; ++c) {
        __syncthreads();                             // drains DMA(c) + a-loads(c)
        float4 aC[TPW];
        #pragma unroll
        for (int t = 0; t < TPW; ++t) aC[t] = areg[t];
        if (c + 1 < NCHUNK) {
            const int kb = (c + 1) * KC;
            #pragma unroll
            for (int j = 0; j < 4; ++j)
                glds16(gw + (size_t)(wv * 4 + j) * HID + kb + 4 * lane,
                       &Wl[(c + 1) & 1][(wv * 4 + j) * KC]);
            #pragma unroll
            for (int t = 0; t < TPW; ++t)
                areg[t] = *(const float4*)&a0[(size_t)t * HID + kb + 4 * lane];
        }
        const float* Wc = &Wl[c & 1][0];
        #pragma unroll
        for (int g = 0; g < NG; ++g) {
            float4 w = *(const float4*)&Wc[g * KC + 4 * lane];
            #pragma unroll
            for (int t = 0; t < TPW; ++t) {
                acc[t*16+g] = fmaf(aC[t].x, w.x, acc[t*16+g]);
                acc[t*16+g] = fmaf(aC[t].y, w.y, acc[t*16+g]);
                acc[t*16+g] = fmaf(aC[t].z, w.z, acc[t*16+g]);
                acc[t*16+g] = fmaf(aC[t].w, w.w, acc[t*16+g]);
            }
        }
    }

    #pragma unroll
    for (int i = 0; i < 32; ++i) acc[i] += __shfl_xor(acc[i], 32);
    RS_ROUND(16, 16) RS_ROUND(8, 8) RS_ROUND(4, 4) RS_ROUND(2, 2) RS_ROUND(1, 1)
    // lane holds logit for (t = (lane>>4)&1, g = lane&15); lanes 32..63 duplicate
    float v = acc[0];
    float mx = v;
    #pragma unroll
    for (int o = 8; o; o >>= 1) mx = fmaxf(mx, __shfl_xor(mx, o));
    float p = expf(v - mx);
    float s = p;
    #pragma unroll
    for (int o = 8; o; o >>= 1) s += __shfl_xor(s, o);
    p /= s;
    float x = p;                                     // sum probs over wave's 2 tokens
    x += __shfl_xor(x, 16);
    if (lane < 16) unsafeAtomicAdd(&gsum[lane], x);
    int gi = lane & 15; float bv = v;                // first-index-wins argmax on fp32
    #pragma unroll
    for (int o = 8; o; o >>= 1) {
        float ov = __shfl_xor(bv, o);
        int   og = __shfl_xor(gi, o);
        if (ov > bv || (ov == bv && og < gi)) { bv = ov; gi = og; }
    }
    if (lane < 32 && (lane & 15) == 0) {             // one leader per token
        int t = t0 + (lane >> 4);
        int pos = atomicAdd(&cnt[gi], 1);
        buckets[gi * N_TOK + pos] = t;
    }
}

// ---------------- mg [g][k][e] -> mgT [g][e][k], full K coverage ----------------
__global__ __launch_bounds__(256) void k_tr(
    const float* __restrict__ mg, float* __restrict__ mgT)
{
    const int g  = blockIdx.x >> 7;                  // 16 g x 128 k-blocks = 2048 blocks
    const int kb = (blockIdx.x & 127) * 64;          // 64 k per block -> covers k 0..8191
    const int e  = threadIdx.x & 15;
    const int kq = threadIdx.x >> 4;                 // 0..15
    const int k0 = kb + 4 * kq;
    const float* src = mg + (size_t)g * HID * NE;
    float4 v;
    v.x = src[(size_t)(k0 + 0) * NE + e];
    v.y = src[(size_t)(k0 + 1) * NE + e];
    v.z = src[(size_t)(k0 + 2) * NE + e];
    v.w = src[(size_t)(k0 + 3) * NE + e];
    *(float4*)&mgT[(size_t)(g * NE + e) * HID + k0] = v;   // coalesced writes
}

// ---------------- build compact (group,tile) worklist ----------------
__global__ void k_sched(const int* __restrict__ cnt, int* __restrict__ sched,
                        int* __restrict__ ntile)
{
    __shared__ int pref[NG + 1];
    if (threadIdx.x == 0) {
        int s = 0;
        for (int g = 0; g < NG; ++g) { pref[g] = s; s += (cnt[g] + TPB - 1) / TPB; }
        pref[NG] = s; *ntile = s;
    }
    __syncthreads();
    int total = pref[NG];
    for (int i = threadIdx.x; i < total; i += blockDim.x) {
        int g = 0;
        while (g < NG - 1 && i >= pref[g + 1]) ++g;
        sched[i] = (g << 16) | (i - pref[g]);
    }
}

// ---------------- Tier-2: mini logits + fused softmax/top-4/output ----------------
__global__ __launch_bounds__(256, 4) void k_mini(
    const float* __restrict__ hid, const float* __restrict__ mgT,
    const int* __restrict__ cnt, const int* __restrict__ buckets,
    const int* __restrict__ sched, const int* __restrict__ ntile,
    float* __restrict__ out, float* __restrict__ esum)
{
    if ((int)blockIdx.x >= *ntile) return;
    const int enc  = sched[blockIdx.x];
    const int g    = enc >> 16;
    const int tile = enc & 0xffff;
    const int n    = cnt[g] - tile * TPB;            // 1..8 valid tokens

    __shared__ float Wl[2][NE * KC];                 // 2 x 16 KB
    __shared__ int   rows[TPB];
    __shared__ float sm[TPB * 16];
    const int tid  = threadIdx.x;
    const int lane = tid & 63;
    const int wv   = tid >> 6;                       // 0..3
    const float* __restrict__ wg = mgT + (size_t)g * NE * HID;

    #pragma unroll
    for (int j = 0; j < 4; ++j)                      // DMA W chunk0 (independent of rows)
        glds16(wg + (size_t)(wv * 4 + j) * HID + 4 * lane, &Wl[0][(wv * 4 + j) * KC]);
    if (tid < TPB)
        rows[tid] = buckets[g * N_TOK + tile * TPB + min(tid, n - 1)];  // clamp dup tail
    __syncthreads();                                 // drains DMA(0) too (once, ok)

    const float* at[TPW];
    #pragma unroll
    for (int t = 0; t < TPW; ++t)
        at[t] = hid + (size_t)rows[wv * TPW + t] * HID + 4 * lane;

    float4 areg[TPW];
    #pragma unroll
    for (int t = 0; t < TPW; ++t)
        areg[t] = *(const float4*)&at[t][0];

    float acc[32];
    #pragma unroll
    for (int i = 0; i < 32; ++i) acc[i] = 0.f;

    for (int c = 0; c < NCHUNK; ++c) {
        if (c) __syncthreads();
        float4 aC[TPW];
        #pragma unroll
        for (int t = 0; t < TPW; ++t) aC[t] = areg[t];
        if (c + 1 < NCHUNK) {
            const int kb = (c + 1) * KC;
            #pragma unroll
            for (int j = 0; j < 4; ++j)
                glds16(wg + (size_t)(wv * 4 + j) * HID + kb + 4 * lane,
                       &Wl[(c + 1) & 1][(wv * 4 + j) * KC]);
            #pragma unroll
            for (int t = 0; t < TPW; ++t)
                areg[t] = *(const float4*)&at[t][kb];
        }
        const float* Wc = &Wl[c & 1][0];
        #pragma unroll
        for (int e = 0; e < NE; ++e) {
            float4 w = *(const float4*)&Wc[e * KC + 4 * lane];
            #pragma unroll
            for (int t = 0; t < TPW; ++t) {
                acc[t*16+e] = fmaf(aC[t].x, w.x, acc[t*16+e]);
                acc[t*16+e] = fmaf(aC[t].y, w.y, acc[t*16+e]);
                acc[t*16+e] = fmaf(aC[t].z, w.z, acc[t*16+e]);
                acc[t*16+e] = fmaf(aC[t].w, w.w, acc[t*16+e]);
            }
        }
    }

    #pragma unroll
    for (int i = 0; i < 32; ++i) acc[i] += __shfl_xor(acc[i], 32);
    RS_ROUND(16, 16) RS_ROUND(8, 8) RS_ROUND(4, 4) RS_ROUND(2, 2) RS_ROUND(1, 1)
    // lane holds logit for (tl = wv*2 + ((lane>>4)&1), e = lane&15); upper 32 dup
    const int tl = wv * TPW + ((lane >> 4) & 1);
    float v = acc[0];
    float mx = v;
    #pragma unroll
    for (int o = 8; o; o >>= 1) mx = fmaxf(mx, __shfl_xor(mx, o));
    float p = expf(v - mx);
    float s = p;
    #pragma unroll
    for (int o = 8; o; o >>= 1) s += __shfl_xor(s, o);
    p /= s;
    float x = (tl < n) ? p : 0.f;                    // exclude dup-clamped tail tokens
    x += __shfl_xor(x, 16);
    if (lane < 16) unsafeAtomicAdd(&esum[lane], x);

    if (lane < 32) sm[tl * 16 + (lane & 15)] = p;    // sm[tl*16 + e]
    __syncthreads();
    if (tid < TPB * 16 && (tid & 15) == 0) {         // leader per token
        int tt = tid >> 4;                           // 0..7
        if (tt < n) {
            float pe[NE];
            #pragma unroll
            for (int e = 0; e < NE; ++e) pe[e] = sm[tt * 16 + e];
            unsigned used = 0;
            float tv[4]; int ti[4];
            #pragma unroll
            for (int j = 0; j < 4; ++j) {
                float best = -1.f; int bi = 0;
                #pragma unroll
                for (int e = 0; e < NE; ++e)
                    if (!((used >> e) & 1u) && pe[e] > best) { best = pe[e]; bi = e; }
                used |= 1u << bi; tv[j] = best; ti[j] = bi;
            }
            float inv4 = 1.f / (tv[0] + tv[1] + tv[2] + tv[3]);   // group prob cancels
            int t = rows[tt];
            #pragma unroll
            for (int j = 0; j < 4; ++j) {
                out[t * 4 + j]             = tv[j] * inv4;
                out[N_TOK * 4 + t * 4 + j] = (float)(g * NE + ti[j]);
            }
        }
    }
}

// ---------------- aux loss scalar ----------------
__global__ void k_aux(const float* __restrict__ gsum, const float* __restrict__ esum,
                      float* __restrict__ out)
{
    if (threadIdx.x == 0) {
        float a = 0.f;
        for (int g = 0; g < NG; ++g) { float m = gsum[g] * (1.f / N_TOK); a += m * m; }
        for (int e = 0; e < NE; ++e) { float m = esum[e] * (1.f / N_TOK); a += m * m; }
        out[N_TOK * 8] = a;   // element 65536
    }
}

extern "C" void kernel_launch(void* const* d_in, const int* in_sizes, int n_in,
                              void* d_out, int out_size, void* d_ws, size_t ws_size,
                              hipStream_t stream) {
    const float* hid = (const float*)d_in[0];   // [8192,8192]
    const float* gw  = (const float*)d_in[1];   // [16,8192]
    const float* mg  = (const float*)d_in[2];   // [16,8192,16]
    float* out = (float*)d_out;
    char*  ws  = (char*)d_ws;
    int*    cnt     = (int*)   (ws + OFF_CNT);
    float*  gsum    = (float*) (ws + OFF_GSUM);
    float*  esum    = (float*) (ws + OFF_ESUM);
    int*    ntile   = (int*)   (ws + OFF_NTIL);
    int*    buckets = (int*)   (ws + OFF_BUCK);
    int*    sched   = (int*)   (ws + OFF_SCHED);
    float*  mgT     = (float*) (ws + OFF_MGT);

    hipMemsetAsync(d_ws, 0, ZERO_BYTES, stream);

    k_tr<<<2048, 256, 0, stream>>>(mg, mgT);
    k_group<<<N_TOK / TPB, 256, 0, stream>>>(hid, gw, cnt, buckets, gsum);
    k_sched<<<1, 256, 0, stream>>>(cnt, sched, ntile);
    k_mini<<<N_TOK / TPB + NG, 256, 0, stream>>>(hid, mgT, cnt, buckets, sched, ntile, out, esum);
    k_aux<<<1, 64, 0, stream>>>(gsum, esum, out);
}